// Round 3
// baseline (347.366 us; speedup 1.0000x reference)
//
#include <hip/hip_runtime.h>

typedef unsigned short u16;
typedef unsigned int u32;
typedef __attribute__((ext_vector_type(8))) short bf16x8;
typedef __attribute__((ext_vector_type(4))) float f32x4;

// Problem constants
static constexpr int B = 16, C = 32, H = 192, W = 192;
static constexpr int HW = H * W;              // 36864
static constexpr int E = 8;
static constexpr int CO = 32;
static constexpr long long NTOT = (long long)B * C * HW; // 18874368
static constexpr float SILU1 = 0.7310585786300049f;      // silu(1), P0 block

__device__ inline u16 f2b(float f) {             // rne float->bf16 bits
    u32 u = __float_as_uint(f);
    return (u16)((u + 0x7fffu + ((u >> 16) & 1u)) >> 16);
}
__device__ inline float b2f(u16 r) { return __uint_as_float((u32)r << 16); }
__device__ inline float silu(float z) { return z / (1.0f + __expf(-z)); }

// ---------------- gate_reduce: per-(b,c) mean of x -------------------------
__global__ __launch_bounds__(256) void gate_reduce(const float* __restrict__ x,
                                                   float* __restrict__ gate_x) {
    const int bc = blockIdx.x;
    const float4* xp = (const float4*)(x + (size_t)bc * HW);
    float s = 0.0f;
    for (int i = threadIdx.x; i < HW / 4; i += 256) {
        float4 v = xp[i];
        s += (v.x + v.y) + (v.z + v.w);
    }
    #pragma unroll
    for (int off = 32; off > 0; off >>= 1) s += __shfl_down(s, off, 64);
    __shared__ float red[4];
    if ((threadIdx.x & 63) == 0) red[threadIdx.x >> 6] = s;
    __syncthreads();
    if (threadIdx.x == 0)
        gate_x[bc] = (red[0] + red[1] + red[2] + red[3]) * (1.0f / HW);
}

// ---------------- basis: g_p = silu(P_p(tanh x)) bf16, [b][y][x][c32] ------
// MODE 0: write 3 precomputed silu planes. MODE 1 (fallback): write t only.
template<int MODE>
__global__ __launch_bounds__(192) void basis_kernel(const float* __restrict__ x,
                                                    u16* __restrict__ g1,
                                                    u16* __restrict__ g2,
                                                    u16* __restrict__ g3,
                                                    const float* __restrict__ beta_w) {
    const int y = blockIdx.x, b = blockIdx.y, tx = threadIdx.x;
    const float beta2 = 2.25f * beta_w[1];
    const float beta3 = (300.0f / 9.0f) * beta_w[2];
    constexpr int NP = (MODE == 0) ? 3 : 1;
    __shared__ __align__(16) u16 pl[NP][192 * 40];   // pixel stride 40 u16 (pad)

    #pragma unroll
    for (int cg = 0; cg < 4; ++cg) {
        u16 r1[8], r2[8], r3[8];
        #pragma unroll
        for (int e = 0; e < 8; ++e) {
            const int c = cg * 8 + e;
            float v = x[((size_t)(b * C + c) * H + y) * W + tx];
            float tt = tanhf(v);
            if constexpr (MODE == 0) {
                float u2 = tt * tt - beta2;
                float u3 = tt * u2 - beta3 * tt;
                r1[e] = f2b(silu(tt));
                r2[e] = f2b(silu(u2));
                r3[e] = f2b(silu(u3));
            } else {
                r1[e] = f2b(tt);
            }
        }
        *(uint4*)&pl[0][tx * 40 + cg * 8] = *(const uint4*)r1;
        if constexpr (MODE == 0) {
            *(uint4*)&pl[1][tx * 40 + cg * 8] = *(const uint4*)r2;
            *(uint4*)&pl[2][tx * 40 + cg * 8] = *(const uint4*)r3;
        }
    }
    __syncthreads();
    const size_t row32 = ((size_t)b * HW + (size_t)y * W) * 32;   // u16 units
    u16* outp[3] = {g1, g2, g3};
    #pragma unroll
    for (int p = 0; p < NP; ++p) {
        uint4* gout = (uint4*)(outp[p] + row32);
        for (int j = tx; j < 768; j += 192)
            gout[j] = *(const uint4*)&pl[p][(j >> 2) * 40 + (j & 3) * 8];
    }
}

// ---------------- prep: wfrag + Sk/Ssum + gating math/loss -----------------
// blocks 0..107: wfrag; block 108: Sk/Ssum; block 109: softmax/top2/loss.
__global__ __launch_bounds__(256) void prep_kernel(const float* __restrict__ gate_x,
                                                   const float* __restrict__ wg,
                                                   const float* __restrict__ pw,
                                                   float* __restrict__ scale,
                                                   float* __restrict__ Sk,
                                                   float* __restrict__ Ssum,
                                                   u16* __restrict__ wfrag,
                                                   float* __restrict__ loss_out) {
    const int blk = blockIdx.x, t = threadIdx.x;
    if (blk < 108) {
        // B-frag: n=co=half*16+(lane&15); k=ci_local=(lane>>4)*8+e
        int j = blk * 256 + t;
        int e = j & 7, lane = (j >> 3) & 63, rest = j >> 9;
        int half = rest & 1, pt = rest >> 1;
        int p = pt / 9, tap = pt - p * 9;
        int co = half * 16 + (lane & 15);
        int ci = 32 + p * 32 + (lane >> 4) * 8 + e;
        wfrag[j] = f2b(pw[(size_t)co * 1152 + ci * 9 + tap]);
        return;
    }
    if (blk == 108) {
        __shared__ float sred[9][32][8];
        __shared__ float sks[288];
        const int co = t & 31, sub = t >> 5;
        #pragma unroll
        for (int k = 0; k < 9; ++k) {
            float s = 0.0f;
            #pragma unroll
            for (int i = 0; i < 4; ++i)
                s += pw[(size_t)co * 1152 + (sub * 4 + i) * 9 + k];
            sred[k][co][sub] = s;
        }
        __syncthreads();
        for (int j = t; j < 288; j += 256) {
            int k = j >> 5, c = j & 31;
            float s = 0.0f;
            #pragma unroll
            for (int u = 0; u < 8; ++u) s += sred[k][c][u];
            sks[j] = s; Sk[j] = s;
        }
        __syncthreads();
        if (t < 32) {
            float s = 0.0f;
            #pragma unroll
            for (int k = 0; k < 9; ++k) s += sks[k * 32 + t];
            Ssum[t] = s;
        }
        return;
    }
    // blk == 109: gating math (gate_x already holds means)
    __shared__ float gsh[B][E];
    if (t < B) {
        float logits[E];
        for (int e = 0; e < E; ++e) {
            float s = 0.0f;
            for (int c = 0; c < C; ++c) s += gate_x[t * C + c] * wg[c * E + e];
            logits[e] = s;
        }
        float m = logits[0];
        for (int e = 1; e < E; ++e) m = fmaxf(m, logits[e]);
        float p[E], sum = 0.0f;
        for (int e = 0; e < E; ++e) { p[e] = expf(logits[e] - m); sum += p[e]; }
        for (int e = 0; e < E; ++e) p[e] /= sum;
        int i0 = 0; float v0 = p[0];
        for (int e = 1; e < E; ++e) if (p[e] > v0) { v0 = p[e]; i0 = e; }
        int i1 = -1; float v1 = -1.0f;
        for (int e = 0; e < E; ++e) { if (e == i0) continue; if (p[e] > v1) { v1 = p[e]; i1 = e; } }
        const float denom = v0 + v1 + 1e-6f;
        const float g0 = v0 / denom, g1 = v1 / denom;
        for (int e = 0; e < E; ++e) gsh[t][e] = 0.0f;
        gsh[t][i0] = g0; gsh[t][i1] = g1;
        scale[t] = g0 + g1;
    }
    __syncthreads();
    __shared__ float impsh[E], loadsh[E];
    if (t < E) {
        float imp = 0.0f, ld = 0.0f;
        for (int b = 0; b < B; ++b) {
            float g = gsh[b][t];
            imp += g;
            if (g > 0.0f) ld += 1.0f;
        }
        impsh[t] = imp; loadsh[t] = ld;
    }
    __syncthreads();
    if (t == 0) {
        float mi = 0.0f, ml = 0.0f;
        for (int e = 0; e < E; ++e) { mi += impsh[e]; ml += loadsh[e]; }
        mi *= (1.0f / E); ml *= (1.0f / E);
        float vi = 0.0f, vl = 0.0f;
        for (int e = 0; e < E; ++e) {
            float di = impsh[e] - mi, dl = loadsh[e] - ml;
            vi += di * di; vl += dl * dl;
        }
        vi *= (1.0f / (E - 1)); vl *= (1.0f / (E - 1));
        *loss_out = (vi / (mi * mi + 1e-10f) + vl / (ml * ml + 1e-10f)) * 0.01f;
    }
}

// ---------------- conv: MFMA implicit-GEMM --------------------------------
// Block: 16x16 spatial tile, all 32 co, 4 waves. Wave w: y-rows 4w..4w+3.
// MODE 0: stage precomputed g planes (pure copy). MODE 1: silu from t.
static constexpr int GSTR = 40;                 // bf16 stride per pixel
template<int MODE>
__global__ __launch_bounds__(256) void conv_mfma(const u16* __restrict__ g1,
                                                 const u16* __restrict__ g2,
                                                 const u16* __restrict__ g3,
                                                 const u16* __restrict__ wfrag,
                                                 const float* __restrict__ beta_w,
                                                 const float* __restrict__ scale,
                                                 const float* __restrict__ Sk,
                                                 const float* __restrict__ Ssum,
                                                 float* __restrict__ out) {
    __shared__ __align__(16) u16 gtile[324 * GSTR];   // 18x18 x 40 bf16 = 25920 B
    const int b = blockIdx.z;
    const int gx0 = blockIdx.x << 4, gy0 = blockIdx.y << 4;
    const int tid = threadIdx.x;
    const int w = tid >> 6, lane = tid & 63, q = lane >> 4, ml = lane & 15;
    const float beta2 = 2.25f * beta_w[1];
    const float beta3 = (300.0f / 9.0f) * beta_w[2];
    const size_t bbase = (size_t)b * HW * 32;         // u16 units

    f32x4 acc[4][2];
    #pragma unroll
    for (int a = 0; a < 4; ++a)
        #pragma unroll
        for (int h = 0; h < 2; ++h)
            acc[a][h] = (f32x4){0.0f, 0.0f, 0.0f, 0.0f};

    #pragma unroll
    for (int p = 0; p < 3; ++p) {
        __syncthreads();                         // protect prior chunk reads
        const u16* gp = (p == 0) ? g1 : (p == 1) ? g2 : g3;
        for (int j = tid; j < 1296; j += 256) {  // 324 pixels x 4 quarters
            int pix = j >> 2, qq = j & 3;
            int py = pix / 18, px = pix - py * 18;
            int gy = gy0 + py - 1, gx = gx0 + px - 1;
            uint4 res;
            if ((unsigned)gy < (unsigned)H && (unsigned)gx < (unsigned)W) {
                if constexpr (MODE == 0) {
                    res = *(const uint4*)(gp + bbase + ((size_t)(gy * W + gx)) * 32 + (qq << 3));
                } else {
                    uint4 val = *(const uint4*)(g1 + bbase + (((size_t)(gy * W + gx)) << 5) + (qq << 3));
                    u16 r8[8];
                    const u16* tv = (const u16*)&val;
                    #pragma unroll
                    for (int e = 0; e < 8; ++e) {
                        float tt = b2f(tv[e]);
                        float u;
                        if (p == 0) u = tt;
                        else if (p == 1) u = tt * tt - beta2;
                        else { float p2v = tt * tt - beta2; u = tt * p2v - beta3 * tt; }
                        r8[e] = f2b(silu(u));
                    }
                    res = *(const uint4*)r8;
                }
            } else {
                res = make_uint4(0u, 0u, 0u, 0u);  // zero-pad halo
            }
            *(uint4*)&gtile[pix * GSTR + (qq << 3)] = res;
        }
        __syncthreads();
        const u16* wf = wfrag + (size_t)p * 9 * 2 * 64 * 8;
        #pragma unroll
        for (int tap = 0; tap < 9; ++tap) {
            const int dy = tap / 3 - 1, dx = tap % 3 - 1;
            bf16x8 b0 = *(const bf16x8*)(wf + ((size_t)(tap * 2 + 0) * 64 + lane) * 8);
            bf16x8 b1 = *(const bf16x8*)(wf + ((size_t)(tap * 2 + 1) * 64 + lane) * 8);
            #pragma unroll
            for (int a = 0; a < 4; ++a) {
                const bf16x8 af = *(const bf16x8*)
                    &gtile[(((w << 2) + a + dy + 1) * 18 + (ml + dx + 1)) * GSTR + (q << 3)];
                acc[a][0] = __builtin_amdgcn_mfma_f32_16x16x32_bf16(af, b0, acc[a][0], 0, 0, 0);
                acc[a][1] = __builtin_amdgcn_mfma_f32_16x16x32_bf16(af, b1, acc[a][1], 0, 0, 0);
            }
        }
    }

    // Epilogue: + P0 bias (border-aware), * scale[b], store.
    const float sc = scale[b];
    const bool interior = (blockIdx.x > 0) && (blockIdx.x < 11) &&
                          (blockIdx.y > 0) && (blockIdx.y < 11);
    #pragma unroll
    for (int half = 0; half < 2; ++half) {
        const int co = half * 16 + ml;
        const float bfull = SILU1 * Ssum[co];
        #pragma unroll
        for (int a = 0; a < 4; ++a) {
            const int y = gy0 + (w << 2) + a;
            float ov[4];
            #pragma unroll
            for (int r = 0; r < 4; ++r) {
                float bias = bfull;
                if (!interior) {
                    const int xg = gx0 + (q << 2) + r;
                    bias = 0.0f;
                    #pragma unroll
                    for (int k = 0; k < 9; ++k) {
                        int yy = y + k / 3 - 1, xx = xg + k % 3 - 1;
                        if ((unsigned)yy < (unsigned)H && (unsigned)xx < (unsigned)W)
                            bias += Sk[k * 32 + co];
                    }
                    bias *= SILU1;
                }
                ov[r] = (acc[a][half][r] + bias) * sc;
            }
            *(float4*)&out[((size_t)(b * CO + co) * H + y) * W + gx0 + (q << 2)] = *(float4*)ov;
        }
    }
}

extern "C" void kernel_launch(void* const* d_in, const int* in_sizes, int n_in,
                              void* d_out, int out_size, void* d_ws, size_t ws_size,
                              hipStream_t stream) {
    const float* x  = (const float*)d_in[0];
    const float* wg = (const float*)d_in[1];
    const float* pw = (const float*)d_in[2];
    const float* bw = (const float*)d_in[3];
    float* out = (float*)d_out;
    char* ws = (char*)d_ws;

    const size_t small = 512 * 4 + 64 + 288 * 4 + 128 + 27648 * 2 + 256;
    const int mode = (ws_size >= (size_t)NTOT * 6 + small) ? 0 : 1;
    const size_t big = (mode == 0) ? (size_t)NTOT * 6 : (size_t)NTOT * 2;

    u16* g1 = (u16*)ws;                               // t in mode 1
    u16* g2 = (u16*)(ws + (size_t)NTOT * 2);
    u16* g3 = (u16*)(ws + (size_t)NTOT * 4);
    float* gate_x = (float*)(ws + big);
    float* sc     = (float*)(ws + big + 512 * 4);
    float* Sk     = (float*)(ws + big + 512 * 4 + 64);
    float* Ssum   = (float*)(ws + big + 512 * 4 + 64 + 288 * 4);
    u16*   wfrag  = (u16*)(ws + big + 512 * 4 + 64 + 288 * 4 + 128);

    gate_reduce<<<dim3(B * C), 256, 0, stream>>>(x, gate_x);
    if (mode == 0)
        basis_kernel<0><<<dim3(H, B), 192, 0, stream>>>(x, g1, g2, g3, bw);
    else
        basis_kernel<1><<<dim3(H, B), 192, 0, stream>>>(x, g1, g2, g3, bw);
    prep_kernel<<<dim3(110), 256, 0, stream>>>(gate_x, wg, pw, sc, Sk, Ssum, wfrag, out + NTOT);
    if (mode == 0)
        conv_mfma<0><<<dim3(12, 12, B), 256, 0, stream>>>(g1, g2, g3, wfrag, bw, sc, Sk, Ssum, out);
    else
        conv_mfma<1><<<dim3(12, 12, B), 256, 0, stream>>>(g1, g2, g3, wfrag, bw, sc, Sk, Ssum, out);
}

// Round 4
// 292.243 us; speedup vs baseline: 1.1886x; 1.1886x over previous
//
#include <hip/hip_runtime.h>

typedef unsigned short u16;
typedef unsigned int u32;
typedef __attribute__((ext_vector_type(8))) short bf16x8;
typedef __attribute__((ext_vector_type(4))) float f32x4;

// Problem constants
static constexpr int B = 16, C = 32, H = 192, W = 192;
static constexpr int HW = H * W;              // 36864
static constexpr int E = 8;
static constexpr int CO = 32;
static constexpr long long NTOT = (long long)B * C * HW; // 18874368
static constexpr float SILU1 = 0.7310585786300049f;      // silu(1), P0 block

// Workspace layout (bytes): t first, then small tables
static constexpr size_t GX_OFF = (size_t)NTOT * 2;           // gate_x: 512 f
static constexpr size_t SK_OFF = GX_OFF + 512 * 4;           // Sk: 288 f
static constexpr size_t SS_OFF = SK_OFF + 288 * 4;           // Ssum: 32 f
static constexpr size_t WF_OFF = SS_OFF + 128;               // wfrag: 27648 bf16

__device__ inline u16 f2b(float f) {             // rne float->bf16 bits
    u32 u = __float_as_uint(f);
    return (u16)((u + 0x7fffu + ((u >> 16) & 1u)) >> 16);
}
__device__ inline float silu(float z) { return z / (1.0f + __expf(-z)); }

// ============ Kernel 1: tanh->t (plane layout) + gate means + prep =========
// blocks 0..511: per-(b,c) plane tanh + mean
// blocks 512..619: wfrag bf16 B-fragments
// block 620: Sk / Ssum
__global__ __launch_bounds__(256) void stage1_prep(const float* __restrict__ x,
                                                   const float* __restrict__ pw,
                                                   u16* __restrict__ t_out,
                                                   float* __restrict__ gate_x,
                                                   float* __restrict__ Sk,
                                                   float* __restrict__ Ssum,
                                                   u16* __restrict__ wfrag) {
    const int blk = blockIdx.x, t = threadIdx.x;
    __shared__ float sred[9][32][8];          // Sk block; [0][0][0..3] reused by stage1
    if (blk < 512) {
        const float4* xp = (const float4*)(x + (size_t)blk * HW);
        ushort4* tp = (ushort4*)(t_out + (size_t)blk * HW);
        float s = 0.0f;
        for (int i = t; i < HW / 4; i += 256) {
            float4 v = xp[i];
            s += (v.x + v.y) + (v.z + v.w);
            ushort4 o;
            o.x = f2b(tanhf(v.x)); o.y = f2b(tanhf(v.y));
            o.z = f2b(tanhf(v.z)); o.w = f2b(tanhf(v.w));
            tp[i] = o;
        }
        #pragma unroll
        for (int off = 32; off > 0; off >>= 1) s += __shfl_down(s, off, 64);
        if ((t & 63) == 0) sred[0][0][t >> 6] = s;
        __syncthreads();
        if (t == 0)
            gate_x[blk] = (sred[0][0][0] + sred[0][0][1] + sred[0][0][2] + sred[0][0][3])
                          * (1.0f / HW);
        return;
    }
    if (blk < 620) {
        // B-frag: n=co=half*16+(lane&15); k=ci_local=(lane>>4)*8+e
        int j = (blk - 512) * 256 + t;
        int e = j & 7, lane = (j >> 3) & 63, rest = j >> 9;
        int half = rest & 1, pt = rest >> 1;
        int p = pt / 9, tap = pt - p * 9;
        int co = half * 16 + (lane & 15);
        int ci = 32 + p * 32 + (lane >> 4) * 8 + e;
        wfrag[j] = f2b(pw[(size_t)co * 1152 + ci * 9 + tap]);
        return;
    }
    // blk == 620: Sk[k][co] = sum_{ci<32} W[co][ci][k]; Ssum[co] = sum_k Sk
    {
        const int co = t & 31, sub = t >> 5;
        #pragma unroll
        for (int k = 0; k < 9; ++k) {
            float s = 0.0f;
            #pragma unroll
            for (int i = 0; i < 4; ++i)
                s += pw[(size_t)co * 1152 + (sub * 4 + i) * 9 + k];
            sred[k][co][sub] = s;
        }
        __syncthreads();
        __shared__ float sks[288];
        for (int j = t; j < 288; j += 256) {
            int k = j >> 5, c = j & 31;
            float s = 0.0f;
            #pragma unroll
            for (int u = 0; u < 8; ++u) s += sred[k][c][u];
            sks[j] = s; Sk[j] = s;
        }
        __syncthreads();
        if (t < 32) {
            float s = 0.0f;
            #pragma unroll
            for (int k = 0; k < 9; ++k) s += sks[k * 32 + t];
            Ssum[t] = s;
        }
    }
}

// ============ Kernel 2: fused gating + silu-basis + MFMA conv ==============
// 16x16 tile, halo 18x18=324 px. 4 waves; wave w: y-rows 4w..4w+3.
// t held in regs (one gather/block); per chunk p: silu->LDS gtile; MFMA with
// A-frag shared across dy (18 ds_read_b128/chunk/wave).
static constexpr int GSTR = 40;                 // u16 per pixel (80 B, bank-balanced)

__global__ __launch_bounds__(256) void conv_mfma(const u16* __restrict__ t_ws,
                                                 const u16* __restrict__ wfrag,
                                                 const float* __restrict__ beta_w,
                                                 const float* __restrict__ gate_x,
                                                 const float* __restrict__ wg,
                                                 const float* __restrict__ Sk,
                                                 const float* __restrict__ Ssum,
                                                 float* __restrict__ out) {
    __shared__ __align__(16) u16 gtile[324 * GSTR];   // 25920 B
    __shared__ float lg[B][E];                         // logits -> gates
    __shared__ float scl[B];

    const int b = blockIdx.z;
    const int gx0 = blockIdx.x << 4, gy0 = blockIdx.y << 4;
    const int tid = threadIdx.x;
    const int w = tid >> 6, lane = tid & 63, q = lane >> 4, ml = lane & 15;
    const float beta2 = 2.25f * beta_w[1];
    const float beta23 = beta2 + (300.0f / 9.0f) * beta_w[2];

    // ---- pixel ownership: p0 = tid; 68 extra pixels spread 17/wave ----
    const int p0 = tid;
    int extra = -1;
    if ((tid & 3) == 0) extra = tid >> 2;                 // 64
    else if ((tid & 63) == 1) extra = 64 + (tid >> 6);    // +4
    const int p1 = (extra >= 0) ? 256 + extra : -1;

    // ---- phase 0: gather t (32 ci per owned pixel) into packed regs ----
    u32 pk0[16], pk1[16];
    bool v0, v1 = false;
    {
        int py = p0 / 18, px = p0 - py * 18;
        int gy = gy0 + py - 1, gx = gx0 + px - 1;
        v0 = (unsigned)gy < (unsigned)H && (unsigned)gx < (unsigned)W;
        #pragma unroll
        for (int cc = 0; cc < 16; ++cc) pk0[cc] = 0u;
        if (v0) {
            const u16* tp = t_ws + (size_t)b * C * HW + gy * W + gx;
            #pragma unroll
            for (int cc = 0; cc < 16; ++cc) {
                u32 lo = tp[(size_t)(2 * cc) * HW];
                u32 hi = tp[(size_t)(2 * cc + 1) * HW];
                pk0[cc] = lo | (hi << 16);
            }
        }
        #pragma unroll
        for (int cc = 0; cc < 16; ++cc) pk1[cc] = 0u;
        if (p1 >= 0) {
            int py1 = p1 / 18, px1 = p1 - py1 * 18;
            int gy1 = gy0 + py1 - 1, gx1 = gx0 + px1 - 1;
            v1 = (unsigned)gy1 < (unsigned)H && (unsigned)gx1 < (unsigned)W;
            if (v1) {
                const u16* tp = t_ws + (size_t)b * C * HW + gy1 * W + gx1;
                #pragma unroll
                for (int cc = 0; cc < 16; ++cc) {
                    u32 lo = tp[(size_t)(2 * cc) * HW];
                    u32 hi = tp[(size_t)(2 * cc + 1) * HW];
                    pk1[cc] = lo | (hi << 16);
                }
            }
        }
    }

    // ---- gating (every block; cheap, L2-hot) ----
    if (tid < 128) {
        int gb = tid >> 3, ge = tid & 7;
        float s = 0.0f;
        #pragma unroll
        for (int c = 0; c < 32; ++c) s += gate_x[gb * 32 + c] * wg[c * 8 + ge];
        lg[gb][ge] = s;
    }
    __syncthreads();
    if (tid < 16) {
        float p[E];
        float m = lg[tid][0];
        #pragma unroll
        for (int e = 1; e < E; ++e) m = fmaxf(m, lg[tid][e]);
        float sum = 0.0f;
        #pragma unroll
        for (int e = 0; e < E; ++e) { p[e] = __expf(lg[tid][e] - m); sum += p[e]; }
        float inv = 1.0f / sum;
        #pragma unroll
        for (int e = 0; e < E; ++e) p[e] *= inv;
        int i0 = 0; float v0g = p[0];
        #pragma unroll
        for (int e = 1; e < E; ++e) if (p[e] > v0g) { v0g = p[e]; i0 = e; }
        int i1 = -1; float v1g = -1.0f;
        #pragma unroll
        for (int e = 0; e < E; ++e) { if (e == i0) continue; if (p[e] > v1g) { v1g = p[e]; i1 = e; } }
        const float denom = v0g + v1g + 1e-6f;
        const float g0 = v0g / denom, g1 = v1g / denom;
        #pragma unroll
        for (int e = 0; e < E; ++e) lg[tid][e] = 0.0f;
        lg[tid][i0] = g0; lg[tid][i1] = g1;
        scl[tid] = g0 + g1;
    }
    __syncthreads();
    if (blockIdx.x == 0 && blockIdx.y == 0 && b == 0 && tid == 0) {
        float imp[E], ld[E];
        #pragma unroll
        for (int e = 0; e < E; ++e) { imp[e] = 0.0f; ld[e] = 0.0f; }
        for (int bb = 0; bb < B; ++bb)
            #pragma unroll
            for (int e = 0; e < E; ++e) {
                float g = lg[bb][e];
                imp[e] += g;
                if (g > 0.0f) ld[e] += 1.0f;
            }
        float mi = 0.0f, mld = 0.0f;
        #pragma unroll
        for (int e = 0; e < E; ++e) { mi += imp[e]; mld += ld[e]; }
        mi *= (1.0f / E); mld *= (1.0f / E);
        float vi = 0.0f, vl = 0.0f;
        #pragma unroll
        for (int e = 0; e < E; ++e) {
            float di = imp[e] - mi, dl = ld[e] - mld;
            vi += di * di; vl += dl * dl;
        }
        vi *= (1.0f / (E - 1)); vl *= (1.0f / (E - 1));
        out[NTOT] = (vi / (mi * mi + 1e-10f) + vl / (mld * mld + 1e-10f)) * 0.01f;
    }

    f32x4 acc[4][2];
    #pragma unroll
    for (int a = 0; a < 4; ++a) {
        acc[a][0] = (f32x4){0.0f, 0.0f, 0.0f, 0.0f};
        acc[a][1] = (f32x4){0.0f, 0.0f, 0.0f, 0.0f};
    }

    // ---- K loop: 3 chunks (P1,P2,P3), t from regs ----
    #pragma unroll
    for (int p = 0; p < 3; ++p) {
        if (p) __syncthreads();                  // prior chunk's reads done
        // silu(P_p) -> gtile for owned pixels
        #pragma unroll
        for (int slot = 0; slot < 2; ++slot) {
            const int pix = slot ? p1 : p0;
            if (slot && p1 < 0) continue;
            const bool vv = slot ? v1 : v0;
            const u32* pk = slot ? pk1 : pk0;
            u32 r[16];
            if (vv) {
                #pragma unroll
                for (int cc = 0; cc < 16; ++cc) {
                    float tl = __uint_as_float(pk[cc] << 16);
                    float th = __uint_as_float(pk[cc] & 0xffff0000u);
                    float ul, uh;
                    if (p == 0) { ul = tl; uh = th; }
                    else if (p == 1) { ul = fmaf(tl, tl, -beta2); uh = fmaf(th, th, -beta2); }
                    else { ul = tl * fmaf(tl, tl, -beta23); uh = th * fmaf(th, th, -beta23); }
                    u32 gl = __float_as_uint(silu(ul)) + 0x8000u;   // round-half-up
                    u32 gh = __float_as_uint(silu(uh)) + 0x8000u;
                    r[cc] = (gl >> 16) | (gh & 0xffff0000u);
                }
            } else {
                #pragma unroll
                for (int cc = 0; cc < 16; ++cc) r[cc] = 0u;
            }
            uint4* dst = (uint4*)&gtile[pix * GSTR];
            dst[0] = *(const uint4*)&r[0];
            dst[1] = *(const uint4*)&r[4];
            dst[2] = *(const uint4*)&r[8];
            dst[3] = *(const uint4*)&r[12];
        }
        __syncthreads();
        // MFMA: dx-grouped, A-frag shared across dy
        const u16* wf = wfrag + (size_t)p * 9216;
        #pragma unroll
        for (int dx = 0; dx < 3; ++dx) {
            bf16x8 bf[3][2];
            #pragma unroll
            for (int dyi = 0; dyi < 3; ++dyi) {
                const int tap = dyi * 3 + dx;
                bf[dyi][0] = *(const bf16x8*)(wf + ((size_t)(tap * 2 + 0) * 64 + lane) * 8);
                bf[dyi][1] = *(const bf16x8*)(wf + ((size_t)(tap * 2 + 1) * 64 + lane) * 8);
            }
            #pragma unroll
            for (int rl = 0; rl < 6; ++rl) {
                const bf16x8 af = *(const bf16x8*)
                    &gtile[(((w << 2) + rl) * 18 + ml + dx) * GSTR + (q << 3)];
                #pragma unroll
                for (int dyi = 0; dyi < 3; ++dyi) {
                    const int a = rl - dyi;
                    if (a >= 0 && a < 4) {
                        acc[a][0] = __builtin_amdgcn_mfma_f32_16x16x32_bf16(af, bf[dyi][0], acc[a][0], 0, 0, 0);
                        acc[a][1] = __builtin_amdgcn_mfma_f32_16x16x32_bf16(af, bf[dyi][1], acc[a][1], 0, 0, 0);
                    }
                }
            }
        }
    }

    // ---- epilogue: P0 bias (border-aware) + scale + store ----
    const float sc = scl[b];
    const bool interior = (blockIdx.x > 0) && (blockIdx.x < 11) &&
                          (blockIdx.y > 0) && (blockIdx.y < 11);
    #pragma unroll
    for (int half = 0; half < 2; ++half) {
        const int co = half * 16 + ml;
        const float bfull = SILU1 * Ssum[co];
        #pragma unroll
        for (int a = 0; a < 4; ++a) {
            const int y = gy0 + (w << 2) + a;
            float ov[4];
            #pragma unroll
            for (int r = 0; r < 4; ++r) {
                float bias = bfull;
                if (!interior) {
                    const int xg = gx0 + (q << 2) + r;
                    bias = 0.0f;
                    #pragma unroll
                    for (int k = 0; k < 9; ++k) {
                        int yy = y + k / 3 - 1, xx = xg + k % 3 - 1;
                        if ((unsigned)yy < (unsigned)H && (unsigned)xx < (unsigned)W)
                            bias += Sk[k * 32 + co];
                    }
                    bias *= SILU1;
                }
                ov[r] = (acc[a][half][r] + bias) * sc;
            }
            *(float4*)&out[((size_t)(b * CO + co) * H + y) * W + gx0 + (q << 2)] = *(float4*)ov;
        }
    }
}

extern "C" void kernel_launch(void* const* d_in, const int* in_sizes, int n_in,
                              void* d_out, int out_size, void* d_ws, size_t ws_size,
                              hipStream_t stream) {
    const float* x  = (const float*)d_in[0];
    const float* wg = (const float*)d_in[1];
    const float* pw = (const float*)d_in[2];
    const float* bw = (const float*)d_in[3];
    float* out = (float*)d_out;
    char* ws = (char*)d_ws;
    u16*   t_ws   = (u16*)ws;
    float* gate_x = (float*)(ws + GX_OFF);
    float* Sk     = (float*)(ws + SK_OFF);
    float* Ssum   = (float*)(ws + SS_OFF);
    u16*   wfrag  = (u16*)(ws + WF_OFF);

    stage1_prep<<<dim3(621), 256, 0, stream>>>(x, pw, t_ws, gate_x, Sk, Ssum, wfrag);
    conv_mfma<<<dim3(12, 12, B), 256, 0, stream>>>(t_ws, wfrag, bw, gate_x, wg, Sk, Ssum, out);
}